// Round 7
// baseline (165.199 us; speedup 1.0000x reference)
//
#include <hip/hip_runtime.h>
#include <hip/hip_bf16.h>
#include <stdint.h>

// Problem constants
#define B_    64
#define T_    200
#define CIN_  80
#define C_    1024
#define M_    (B_ * T_)   // 12800
#define BCEL  (B_ * C_)   // 65536

typedef __attribute__((ext_vector_type(4))) float f32x4;
typedef __attribute__((ext_vector_type(8))) _Float16 f16x8;   // 8 f16 in 4 VGPRs
typedef __attribute__((ext_vector_type(4))) unsigned int u32x4;

// ---------------------------------------------------------------------------
// f32 GEMM (vector ALU) for the pointwise conv: C[M,N] = A[M,K]*B[N,K]^T + bias
// Per-output FMA chain strict ascending-k — bit-identical to rounds 1..6.
// ---------------------------------------------------------------------------
__global__ __launch_bounds__(256) void gemm_abt(
    const float* __restrict__ A, const float* __restrict__ Bm,
    const float* __restrict__ bias, float* __restrict__ C,
    int M, int N, int K) {
  __shared__ float As[16][64];
  __shared__ float Bs[16][64];
  const int tid = threadIdx.x;
  const int tx = tid & 15;
  const int ty = tid >> 4;
  const int m0 = blockIdx.x * 64;
  const int n0 = blockIdx.y * 64;
  const int lr = tid >> 2;
  const int lc = (tid & 3) * 4;

  float acc[4][4] = {{0.f,0.f,0.f,0.f},{0.f,0.f,0.f,0.f},
                     {0.f,0.f,0.f,0.f},{0.f,0.f,0.f,0.f}};
  const float* Aro = A + (size_t)(m0 + lr) * K + lc;
  const float* Bro = Bm + (size_t)(n0 + lr) * K + lc;

  float4 a4 = *(const float4*)(Aro);
  float4 b4 = *(const float4*)(Bro);

  for (int k0 = 0; k0 < K; k0 += 16) {
    __syncthreads();
    As[lc + 0][lr] = a4.x; As[lc + 1][lr] = a4.y;
    As[lc + 2][lr] = a4.z; As[lc + 3][lr] = a4.w;
    Bs[lc + 0][lr] = b4.x; Bs[lc + 1][lr] = b4.y;
    Bs[lc + 2][lr] = b4.z; Bs[lc + 3][lr] = b4.w;
    __syncthreads();
    if (k0 + 16 < K) {
      a4 = *(const float4*)(Aro + k0 + 16);
      b4 = *(const float4*)(Bro + k0 + 16);
    }
#pragma unroll
    for (int kk = 0; kk < 16; ++kk) {
      float4 av = *(const float4*)&As[kk][ty * 4];
      float4 bv = *(const float4*)&Bs[kk][tx * 4];
      acc[0][0] = fmaf(av.x, bv.x, acc[0][0]);
      acc[0][1] = fmaf(av.x, bv.y, acc[0][1]);
      acc[0][2] = fmaf(av.x, bv.z, acc[0][2]);
      acc[0][3] = fmaf(av.x, bv.w, acc[0][3]);
      acc[1][0] = fmaf(av.y, bv.x, acc[1][0]);
      acc[1][1] = fmaf(av.y, bv.y, acc[1][1]);
      acc[1][2] = fmaf(av.y, bv.z, acc[1][2]);
      acc[1][3] = fmaf(av.y, bv.w, acc[1][3]);
      acc[2][0] = fmaf(av.z, bv.x, acc[2][0]);
      acc[2][1] = fmaf(av.z, bv.y, acc[2][1]);
      acc[2][2] = fmaf(av.z, bv.z, acc[2][2]);
      acc[2][3] = fmaf(av.z, bv.w, acc[2][3]);
      acc[3][0] = fmaf(av.w, bv.x, acc[3][0]);
      acc[3][1] = fmaf(av.w, bv.y, acc[3][1]);
      acc[3][2] = fmaf(av.w, bv.z, acc[3][2]);
      acc[3][3] = fmaf(av.w, bv.w, acc[3][3]);
    }
  }

  float bj[4] = {0.f, 0.f, 0.f, 0.f};
  if (bias) {
#pragma unroll
    for (int j = 0; j < 4; ++j) bj[j] = bias[n0 + tx * 4 + j];
  }
#pragma unroll
  for (int i = 0; i < 4; ++i) {
    int m = m0 + ty * 4 + i;
    float4 o4;
    o4.x = acc[i][0] + bj[0];
    o4.y = acc[i][1] + bj[1];
    o4.z = acc[i][2] + bj[2];
    o4.w = acc[i][3] + bj[3];
    *(float4*)&C[(size_t)m * N + n0 + tx * 4] = o4;
  }
}

// ---------------------------------------------------------------------------
// Depthwise conv (K=7, same pad) + BN1 + LIF1 scan, chunked T by 8 with
// 8-deep load prefetch. p:[B,T,C] f32 -> spike f16 bits in s1:[T,B,C].
// ---------------------------------------------------------------------------
__global__ __launch_bounds__(256) void dw_bn_lif(
    const float* __restrict__ p, const float* __restrict__ dw_w,
    const float* __restrict__ dw_b, const float* __restrict__ gam,
    const float* __restrict__ bet, const float* __restrict__ mu,
    const float* __restrict__ var, ushort* __restrict__ s1) {
  int gid = blockIdx.x * blockDim.x + threadIdx.x;
  int b = gid >> 10;
  int o = gid & 1023;

  float w[7];
#pragma unroll
  for (int k = 0; k < 7; ++k) w[k] = dw_w[o * 7 + k];
  float db = dw_b[o];
  float inv = (float)((double)gam[o] / sqrt((double)var[o] + 1e-5));
  float add = (float)((double)bet[o] - (double)mu[o] * (double)inv);

  const float* pp = p + (size_t)b * T_ * C_ + o;
  float win[14];
  win[0] = 0.f; win[1] = 0.f; win[2] = 0.f;
#pragma unroll
  for (int i = 0; i < 11; ++i) win[3 + i] = pp[(size_t)i * C_];

  float v = 0.f;
  size_t obase = (size_t)b * C_ + o;
  for (int c = 0; c < T_ / 8; ++c) {
    int t0 = c * 8;
    float nx[8];
#pragma unroll
    for (int j = 0; j < 8; ++j) {
      int tn = t0 + 11 + j;
      nx[j] = (tn < T_) ? pp[(size_t)tn * C_] : 0.f;
    }
#pragma unroll
    for (int s = 0; s < 8; ++s) {
      float u = db;
#pragma unroll
      for (int k = 0; k < 7; ++k) u = fmaf(w[k], win[s + k], u);
      u = fmaf(u, inv, add);
      v = fmaf(0.5f, v, u);
      bool sp = (v - 1.0f) >= 0.0f;
      s1[obase + (size_t)(t0 + s) * BCEL] = sp ? (ushort)0x3C00 : (ushort)0;
      v = sp ? 0.0f : v;
    }
#pragma unroll
    for (int i = 0; i < 6; ++i) win[i] = win[i + 8];
#pragma unroll
    for (int j = 0; j < 8; ++j) win[6 + j] = nx[j];
  }
}

// ---------------------------------------------------------------------------
// Scaled 2-way f16 split of the linear weights: w ~= w0 + 2^-11 w1s.
// Exact when multiplied by {0,1} spikes (products exact, f32 accum).
// ---------------------------------------------------------------------------
__global__ __launch_bounds__(256) void split_w(
    const float* __restrict__ w, ushort* __restrict__ w0,
    ushort* __restrict__ w1, int n) {
  int i = blockIdx.x * 256 + threadIdx.x;
  if (i >= n) return;
  float x = w[i];
  union { _Float16 h; ushort u; } h0, h1;
  h0.h = (_Float16)x;
  if (fabsf(x) < 6.1035156e-5f) h0.u = 0;   // keep w0 out of f16 subnormals
  float r = x - (float)h0.h;
  h1.h = (_Float16)(r * 2048.0f);
  w0[i] = h0.u;
  w1[i] = h1.u;
}

// ---------------------------------------------------------------------------
// MFMA f16 GEMM, 2-term weight split, single accumulator:
//   y = S*w0^T + (S&0x1000)*w1s^T
// Counted-vmcnt pipeline (T4): B tiles in LDS, 3 buffers, staged 2 K-steps
// ahead; top-of-step sync = s_waitcnt vmcnt(8) + raw s_barrier (never drain
// to 0 in the loop). A (spikes) loads global->VGPR directly, 1 step ahead,
// ping-pong regs (static indexing). B LDS keeps the r6 XOR swizzle
// (proven 0 bank conflicts). 48 KB LDS -> 3 blocks/CU.
// ---------------------------------------------------------------------------
#define BM 128
#define BN 128
#define BKg 32
#define NSTEP (C_ / BKg)   // 32

__global__ __launch_bounds__(256) void gemm_mfma2c(
    const ushort* __restrict__ A,
    const ushort* __restrict__ B0,
    const ushort* __restrict__ B1,
    float* __restrict__ Cout) {
  const int K = C_;
  const int N = C_;
  __shared__ __align__(16) ushort lds[3][2][BN * BKg];   // 48 KB

  const int tid  = threadIdx.x;
  const int lane = tid & 63;
  const int wm = ((tid >> 6) >> 1) * 64;
  const int wn = ((tid >> 6) & 1) * 64;

  // XCD-aware swizzle: 800 blocks -> 100 contiguous per XCD
  int lin = blockIdx.x;
  int qq = gridDim.x >> 3;                 // 100
  int wg = (lin & 7) * qq + (lin >> 3);
  const int m0 = (wg >> 3) * BM;
  const int n0 = (wg & 7) * BN;

  // B staging geometry + source-side inverse swizzle (r6-proven)
  const int r0 = tid >> 2, r1 = r0 + 64;
  const int kc = (tid & 3) * 8;
  const int ks = kc ^ (((tid >> 3) & 3) << 3);

  // read-side fragment indices (swizzled column)
  const int fr = lane & 15;
  const int k8 = (lane >> 4) * 8;
  const int k8s = k8 ^ (((fr >> 1) & 3) << 3);

  // A fragment base: row = m0 + wm + m*16 + fr, col base k8
  const ushort* Af = A + (size_t)(m0 + wm + fr) * K + k8;

  f32x4 acc[4][4] = {};
  f16x8 af_a[4], af_b[4];

#define BSTAGE(bufi, kk0)                                                      \
  do {                                                                         \
    int kk_ = (kk0) < K ? (kk0) : 0;                                           \
    __builtin_amdgcn_global_load_lds(                                          \
        (const __attribute__((address_space(1))) uint32_t*)(B0 + (size_t)(n0 + r0) * K + kk_ + ks),  \
        (__attribute__((address_space(3))) uint32_t*)&lds[bufi][0][tid * 8], 16, 0, 0);              \
    __builtin_amdgcn_global_load_lds(                                          \
        (const __attribute__((address_space(1))) uint32_t*)(B0 + (size_t)(n0 + r1) * K + kk_ + ks),  \
        (__attribute__((address_space(3))) uint32_t*)&lds[bufi][0][(tid + 256) * 8], 16, 0, 0);      \
    __builtin_amdgcn_global_load_lds(                                          \
        (const __attribute__((address_space(1))) uint32_t*)(B1 + (size_t)(n0 + r0) * K + kk_ + ks),  \
        (__attribute__((address_space(3))) uint32_t*)&lds[bufi][1][tid * 8], 16, 0, 0);              \
    __builtin_amdgcn_global_load_lds(                                          \
        (const __attribute__((address_space(1))) uint32_t*)(B1 + (size_t)(n0 + r1) * K + kk_ + ks),  \
        (__attribute__((address_space(3))) uint32_t*)&lds[bufi][1][(tid + 256) * 8], 16, 0, 0);      \
  } while (0)

#define ALOAD(dst, kk0)                                                        \
  do {                                                                         \
    int ka_ = (kk0) < K ? (kk0) : 0;                                           \
    dst[0] = *(const f16x8*)(Af + (size_t)(0)  * K + ka_);                     \
    dst[1] = *(const f16x8*)(Af + (size_t)(16) * K + ka_);                     \
    dst[2] = *(const f16x8*)(Af + (size_t)(32) * K + ka_);                     \
    dst[3] = *(const f16x8*)(Af + (size_t)(48) * K + ka_);                     \
  } while (0)

  // STEP s: wait B(s) landed (allow A(s)+B(s+1)=8 in flight), barrier,
  // ds_read B frags, issue A(s+1) then B(s+2), run 32 MFMAs on af_use.
#define STEP(s, af_use, af_ld, bi_rd, bi_st)                                   \
  do {                                                                         \
    asm volatile("s_waitcnt vmcnt(8)" ::: "memory");                           \
    __builtin_amdgcn_sched_barrier(0);                                         \
    __builtin_amdgcn_s_barrier();                                              \
    __builtin_amdgcn_sched_barrier(0);                                         \
    f16x8 b0f[4], b1f[4];                                                      \
    _Pragma("unroll")                                                          \
    for (int n = 0; n < 4; ++n) {                                              \
      b0f[n] = *(const f16x8*)&lds[bi_rd][0][(wn + n * 16 + fr) * BKg + k8s];  \
      b1f[n] = *(const f16x8*)&lds[bi_rd][1][(wn + n * 16 + fr) * BKg + k8s];  \
    }                                                                          \
    ALOAD(af_ld, ((s) + 1) * BKg);                                             \
    BSTAGE(bi_st, ((s) + 2) * BKg);                                            \
    _Pragma("unroll")                                                          \
    for (int m = 0; m < 4; ++m) {                                              \
      union HU { f16x8 h; u32x4 u; } t, t2;                                    \
      t.h = af_use[m];                                                         \
      t2.u = t.u & 0x10001000u;   /* {0,1.0f16} -> {0, 2^-11} exactly */       \
      _Pragma("unroll")                                                        \
      for (int n = 0; n < 4; ++n) {                                            \
        acc[m][n] = __builtin_amdgcn_mfma_f32_16x16x32_f16(                    \
            af_use[m], b0f[n], acc[m][n], 0, 0, 0);                            \
        acc[m][n] = __builtin_amdgcn_mfma_f32_16x16x32_f16(                    \
            t2.h, b1f[n], acc[m][n], 0, 0, 0);                                 \
      }                                                                        \
    }                                                                          \
  } while (0)

  // prologue: B(0), A(0), B(1)  (issue order matters for vmcnt counting)
  BSTAGE(0, 0);
  ALOAD(af_a, 0);
  BSTAGE(1, BKg);

  int bi0 = 0;  // buffer holding step s
  for (int s = 0; s < NSTEP; s += 2) {
    int bi1 = bi0 + 1; if (bi1 == 3) bi1 = 0;
    int bi2 = bi1 + 1; if (bi2 == 3) bi2 = 0;
    STEP(s,     af_a, af_b, bi0, bi2);   // reads buf s,   stages buf s+2
    STEP(s + 1, af_b, af_a, bi1, bi0);   // reads buf s+1, stages buf s+3
    bi0 = bi2;
  }
#undef STEP
#undef ALOAD
#undef BSTAGE

  // epilogue: C/D layout col=lane&15, row=(lane>>4)*4+j
  const int ccol = lane & 15;
  const int crow = (lane >> 4) * 4;
#pragma unroll
  for (int m = 0; m < 4; ++m)
#pragma unroll
    for (int n = 0; n < 4; ++n)
#pragma unroll
      for (int j = 0; j < 4; ++j) {
        int row = m0 + wm + m * 16 + crow + j;
        int col = n0 + wn + n * 16 + ccol;
        Cout[(size_t)row * N + col] = acc[m][n][j];
      }
}

// ---------------------------------------------------------------------------
// BN2 + LIF2 + residual, chunked T by 8 with next-chunk prefetch.
// Safe when y == out (owner-thread read-before-write per element).
// ---------------------------------------------------------------------------
__global__ __launch_bounds__(256) void bn_lif_add(
    const float* __restrict__ y, const ushort* __restrict__ s1b,
    const float* __restrict__ gam, const float* __restrict__ bet,
    const float* __restrict__ mu, const float* __restrict__ var,
    float* __restrict__ out) {
  int gid = blockIdx.x * blockDim.x + threadIdx.x;
  int o = gid & 1023;

  float inv = (float)((double)gam[o] / sqrt((double)var[o] + 1e-5));
  float add = (float)((double)bet[o] - (double)mu[o] * (double)inv);

  float v = 0.f;
  size_t base = (size_t)gid;
  float yv[8]; ushort sv[8];
#pragma unroll
  for (int j = 0; j < 8; ++j) {
    yv[j] = y[base + (size_t)j * BCEL];
    sv[j] = s1b[base + (size_t)j * BCEL];
  }
  for (int c = 0; c < T_ / 8; ++c) {
    int t0 = c * 8;
    float yn[8] = {0,0,0,0,0,0,0,0}; ushort sn[8] = {0,0,0,0,0,0,0,0};
    if (c + 1 < T_ / 8) {
#pragma unroll
      for (int j = 0; j < 8; ++j) {
        size_t idx = base + (size_t)(t0 + 8 + j) * BCEL;
        yn[j] = y[idx];
        sn[j] = s1b[idx];
      }
    }
#pragma unroll
    for (int j = 0; j < 8; ++j) {
      float u = fmaf(yv[j], inv, add);
      v = fmaf(0.5f, v, u);
      bool sp = (v - 1.0f) >= 0.0f;
      float s1v = sv[j] ? 1.0f : 0.0f;
      out[base + (size_t)(t0 + j) * BCEL] = (sp ? 1.0f : 0.0f) + s1v;
      v = sp ? 0.0f : v;
    }
#pragma unroll
    for (int j = 0; j < 8; ++j) { yv[j] = yn[j]; sv[j] = sn[j]; }
  }
}

// ---------------------------------------------------------------------------
extern "C" void kernel_launch(void* const* d_in, const int* in_sizes, int n_in,
                              void* d_out, int out_size, void* d_ws,
                              size_t ws_size, hipStream_t stream) {
  const float* x     = (const float*)d_in[0];
  const float* pw_w  = (const float*)d_in[1];
  const float* pw_b  = (const float*)d_in[2];
  const float* dw_w  = (const float*)d_in[3];
  const float* dw_b  = (const float*)d_in[4];
  const float* bn1g  = (const float*)d_in[5];
  const float* bn1b  = (const float*)d_in[6];
  const float* bn1m  = (const float*)d_in[7];
  const float* bn1v  = (const float*)d_in[8];
  const float* lin_w = (const float*)d_in[9];
  const float* bn2g  = (const float*)d_in[10];
  const float* bn2b  = (const float*)d_in[11];
  const float* bn2m  = (const float*)d_in[12];
  const float* bn2v  = (const float*)d_in[13];

  char* wsb  = (char*)d_ws;
  char* outb = (char*)d_out;
  const size_t PB  = (size_t)M_ * C_ * 4;        // 52,428,800  (p / y, f32)
  const size_t SBB = (size_t)M_ * C_ * 2;        // 26,214,400  (spikes, f16)

  float* p = (float*)d_ws;                       // [B,T,C] f32

  const bool primary = ws_size >= PB + SBB;
  // primary : spikes @ ws+PB, lin-weights @ d_out[0:4MB), y @ ws[0:PB)
  // fallback: spikes @ d_out, memcpy -> ws[0:SBB), weights @ ws+SBB, y @ d_out
  ushort* spikes = primary ? (ushort*)(wsb + PB) : (ushort*)d_out;
  ushort* w0  = primary ? (ushort*)outb : (ushort*)(wsb + SBB);
  ushort* w1s = w0 + (size_t)C_ * C_;
  ushort* Sgemm = primary ? spikes : (ushort*)d_ws;
  float* ybuf = primary ? (float*)d_ws : (float*)d_out;

  // 1) pointwise conv (f32 vector GEMM, exact): p = x . pw_w^T + pw_b
  dim3 pw_grid(M_ / 64, C_ / 64);
  gemm_abt<<<pw_grid, 256, 0, stream>>>(x, pw_w, pw_b, p, M_, C_, CIN_);

  // 2) depthwise + BN1 + LIF1 -> f16 spike bits [T,B,C]
  dw_bn_lif<<<BCEL / 256, 256, 0, stream>>>(p, dw_w, dw_b, bn1g, bn1b, bn1m,
                                            bn1v, spikes);

  // 3) fallback only: move spikes out of d_out before GEMM overwrites it
  if (!primary)
    hipMemcpyAsync(d_ws, d_out, SBB, hipMemcpyDeviceToDevice, stream);

  // 4) linear weight split
  split_w<<<(C_ * C_ + 255) / 256, 256, 0, stream>>>(lin_w, w0, w1s, C_ * C_);

  // 5) linear MFMA GEMM (counted-vmcnt pipeline): y = S.(w0 + 2^-11 w1s)^T
  gemm_mfma2c<<<(M_ / BM) * (C_ / BN), 256, 0, stream>>>(Sgemm, w0, w1s, ybuf);

  // 6) BN2 + LIF2 + residual -> d_out
  bn_lif_add<<<BCEL / 256, 256, 0, stream>>>(ybuf, Sgemm, bn2g, bn2b, bn2m,
                                             bn2v, (float*)d_out);
}